// Round 6
// baseline (206.152 us; speedup 1.0000x reference)
//
#include <hip/hip_runtime.h>
#include <hip/hip_bf16.h>

// DotAttention: B=64, S=4096, H=1024, f32 inputs, f32 outputs.
// out layout (flat f32): [B, 2H] concat(context, dec)  then  [B, S] weights.
//
// Split-S single-pass-over-enc with online softmax, templated on chunk count:
//   NC=20 (5 blocks/CU, 20 waves/CU) when ws_size allows, else NC=16.
//   pass_a  : per (b, chunk) -> partial (ctx[H], m, l) + raw scores
//   finalize: merge NC partials per batch, emit f32 outputs (4 blocks/batch)

#define NB 64
#define NS 4096
#define NH 1024
#define NTHREADS 256
#define NWAVES 4
#define PSTRIDE (NH + 2)              // ctx[NH], m, l

template<int NC>
__global__ __launch_bounds__(NTHREADS, 5)
void dotattn_pass_a(const float* __restrict__ enc, const float* __restrict__ dec,
                    float* __restrict__ scores, float* __restrict__ partials)
{
    const int blk   = blockIdx.x;
    const int b     = blk / NC;
    const int chunk = blk % NC;
    const int tid   = threadIdx.x;
    const int lane  = tid & 63;
    const int wave  = tid >> 6;

    const int start = (chunk * NS) / NC;
    const int end   = ((chunk + 1) * NS) / NC;

    // Lane owns h-slice {lane*4 + k*256 + j : k,j in 0..3} (16 of 1024).
    const float* decb = dec + b * NH;
    float4 dreg[4];
#pragma unroll
    for (int k = 0; k < 4; ++k)
        dreg[k] = *reinterpret_cast<const float4*>(decb + lane * 4 + k * 256);

    float4 ctx[4];
#pragma unroll
    for (int k = 0; k < 4; ++k) ctx[k] = make_float4(0.f, 0.f, 0.f, 0.f);
    float m = -3.0e38f, l = 0.f;

    const float* encb = enc + (size_t)b * NS * NH;

    // prefetch first row for this wave
    float4 en[4];
    {
        const size_t base = (size_t)(start + wave) * NH + lane * 4;
#pragma unroll
        for (int k = 0; k < 4; ++k)
            en[k] = *reinterpret_cast<const float4*>(encb + base + k * 256);
    }

    for (int s = start + wave; s < end; s += NWAVES) {
        float4 e[4];
#pragma unroll
        for (int k = 0; k < 4; ++k) e[k] = en[k];

        if (s + NWAVES < end) {                    // prefetch next row
            const size_t nbase = (size_t)(s + NWAVES) * NH + lane * 4;
#pragma unroll
            for (int k = 0; k < 4; ++k)
                en[k] = *reinterpret_cast<const float4*>(encb + nbase + k * 256);
        }

        float p = 0.f;
#pragma unroll
        for (int k = 0; k < 4; ++k) {
            p += e[k].x * dreg[k].x;
            p += e[k].y * dreg[k].y;
            p += e[k].z * dreg[k].z;
            p += e[k].w * dreg[k].w;
        }
#pragma unroll
        for (int off = 32; off >= 1; off >>= 1)
            p += __shfl_xor(p, off, 64);            // row score on every lane

        if (lane == 0) scores[b * NS + s] = p;

        if (p > m) {                                // wave-uniform branch
            const float sc = __expf(m - p);
            l *= sc;
#pragma unroll
            for (int k = 0; k < 4; ++k) {
                ctx[k].x *= sc; ctx[k].y *= sc; ctx[k].z *= sc; ctx[k].w *= sc;
            }
            m = p;
        }
        const float w = __expf(p - m);
        l += w;
#pragma unroll
        for (int k = 0; k < 4; ++k) {               // reuse enc row in-register
            ctx[k].x += w * e[k].x; ctx[k].y += w * e[k].y;
            ctx[k].z += w * e[k].z; ctx[k].w += w * e[k].w;
        }
    }

    // ---- combine 4 waves -> one partial per block ----
    __shared__ float sml[NWAVES][2];
    __shared__ float sctx[NWAVES][NH];             // 16 KiB

    if (lane == 0) { sml[wave][0] = m; sml[wave][1] = l; }
    __syncthreads();

    const float M = fmaxf(fmaxf(sml[0][0], sml[1][0]), fmaxf(sml[2][0], sml[3][0]));
    float L = 0.f;
#pragma unroll
    for (int wv = 0; wv < NWAVES; ++wv)
        L += sml[wv][1] * __expf(sml[wv][0] - M);

    const float msc = __expf(m - M);               // wave-uniform
#pragma unroll
    for (int k = 0; k < 4; ++k) {
        float4 v = make_float4(ctx[k].x * msc, ctx[k].y * msc,
                               ctx[k].z * msc, ctx[k].w * msc);
        *reinterpret_cast<float4*>(&sctx[wave][lane * 4 + k * 256]) = v;
    }
    __syncthreads();

    float* outp = partials + (size_t)(b * NC + chunk) * PSTRIDE;
    for (int h = tid; h < NH; h += NTHREADS)
        outp[h] = sctx[0][h] + sctx[1][h] + sctx[2][h] + sctx[3][h];
    if (tid == 0) { outp[NH] = M; outp[NH + 1] = L; }
}

template<int NC>
__global__ __launch_bounds__(NTHREADS)
void dotattn_finalize(const float* __restrict__ dec, const float* __restrict__ scores,
                      const float* __restrict__ partials, float* __restrict__ out)
{
    const int b   = blockIdx.x >> 2;               // batch
    const int q   = blockIdx.x & 3;                // quarter
    const int tid = threadIdx.x;
    const float* pb = partials + (size_t)b * NC * PSTRIDE;

    float M = -3.0e38f;
#pragma unroll
    for (int c = 0; c < NC; ++c)
        M = fmaxf(M, pb[c * PSTRIDE + NH]);

    float scale[NC];
    float L = 0.f;
#pragma unroll
    for (int c = 0; c < NC; ++c) {
        scale[c] = __expf(pb[c * PSTRIDE + NH] - M);
        L += pb[c * PSTRIDE + NH + 1] * scale[c];
    }
    const float invL = 1.0f / L;

    // context + dec quarter: h in [q*256, q*256+256)
    {
        const int h = q * 256 + tid;
        float acc = 0.f;
#pragma unroll
        for (int c = 0; c < NC; ++c)
            acc += pb[c * PSTRIDE + h] * scale[c];
        float* ob = out + (size_t)b * 2 * NH;
        ob[h]      = acc * invL;                    // context
        ob[NH + h] = dec[b * NH + h];               // dec passthrough
    }

    // weights quarter: s in [q*1024, q*1024+1024)
    const float* sc = scores + (size_t)b * NS + q * 1024;
    float* wb = out + (size_t)NB * 2 * NH + (size_t)b * NS + q * 1024;
    for (int s = tid; s < 1024; s += NTHREADS)
        wb[s] = __expf(sc[s] - M) * invL;
}

extern "C" void kernel_launch(void* const* d_in, const int* in_sizes, int n_in,
                              void* d_out, int out_size, void* d_ws, size_t ws_size,
                              hipStream_t stream)
{
    // Disambiguate inputs by element count (dec = 65536, enc = 268435456).
    const float* enc;
    const float* dec;
    if (in_sizes[0] == NB * NH) {
        dec = (const float*)d_in[0];
        enc = (const float*)d_in[1];
    } else {
        enc = (const float*)d_in[0];
        dec = (const float*)d_in[1];
    }
    float* out = (float*)d_out;

    float* scores   = (float*)d_ws;                         // f32[64*4096], 1 MiB
    float* partials = scores + (size_t)NB * NS;

    const size_t need20 = (size_t)NB * NS * 4 + (size_t)NB * 20 * PSTRIDE * 4; // ~6.3 MiB
    if (ws_size >= need20) {
        // 20 chunks/batch -> 1280 blocks = 5 blocks/CU = 20 waves/CU
        dotattn_pass_a<20><<<NB * 20, NTHREADS, 0, stream>>>(enc, dec, scores, partials);
        dotattn_finalize<20><<<NB * 4, NTHREADS, 0, stream>>>(dec, scores, partials, out);
    } else {
        // proven-safe fallback: 16 chunks/batch (5.25 MiB ws)
        dotattn_pass_a<16><<<NB * 16, NTHREADS, 0, stream>>>(enc, dec, scores, partials);
        dotattn_finalize<16><<<NB * 4, NTHREADS, 0, stream>>>(dec, scores, partials, out);
    }
}